// Round 10
// baseline (1138.451 us; speedup 1.0000x reference)
//
#include <hip/hip_runtime.h>
#include <hip/hip_bf16.h>

// ---- VQ-VAE forward, round 10 ---------------------------------------------
// r9 post-mortem: occupancy lever neutral (1103->1106); all heavy kernels sit
// at ~2.8 TB/s effective HBM => traffic-bound. r10 cuts bytes via cache
// locality, keeping grids: (1) dconv_k for dc1/dc2 -- whole per-(cls,cog) B
// staged in LDS once (64/32 KB, 1 barrier), kc-OUTER tap-INNER so per-kc
// block footprint ~18KB -> resident/XCD ~2.4MB < 4MB L2 -> tap re-reads hit
// L2 not HBM. (2) conv4 loops reordered kc-outer (per-kc footprint 1/4,
// dw-reuse in L1). No dtype/grid changes.
// Layouts (HW-verified): 32x32x16_bf16 A[m=lane&31][k=(lane>>5)*8+j],
//   D: col=lane&31, row=(reg&3)+8*(reg>>2)+4*(lane>>5).
// 16x16x32_bf16 A[m=lane&15][k=(lane>>4)*8+j], D: col=lane&15,
//   row=(lane>>4)*4+reg.
// Deconv k4s2p1 parity (a,b): out(2q+a,2r+b) += in(q+a-i, r+b-j)*
//   w[ci][co][2i+1-a][2j+1-b]  (verified r2-r9).

typedef __attribute__((ext_vector_type(8))) short short8;
typedef __attribute__((ext_vector_type(16))) float f32x16;
typedef __attribute__((ext_vector_type(4))) float f32x4;

__device__ __forceinline__ unsigned short f2bf(float f) {
  union { __hip_bfloat16 b; unsigned short u; } cv;
  cv.b = __float2bfloat16(f);
  return cv.u;
}
__device__ __forceinline__ unsigned pack2bf(float a, float b) {
  return (unsigned)f2bf(a) | ((unsigned)f2bf(b) << 16);
}

// ---------------- weight repack: conv layers  w[CO][CI][NTAP] fp32 -> frags
// layout: [tap][kc][ntall][lane][8]
template<int CI, int NTAP, int NTALL>
__global__ void repack_conv_w(const float* __restrict__ w,
                              unsigned short* __restrict__ wb, int co_real) {
  const int KC = CI / 16;
  const int total = NTAP * KC * NTALL * 512;
  int i = blockIdx.x * 256 + threadIdx.x;
  if (i >= total) return;
  int j = i & 7, lane = (i >> 3) & 63, t2 = i >> 9;
  int nt = t2 % NTALL; t2 /= NTALL;
  int kc = t2 % KC; int tap = t2 / KC;
  int co = nt * 32 + (lane & 31);
  int ci = kc * 16 + (lane >> 5) * 8 + j;
  float v = (co < co_real) ? w[(co * CI + ci) * NTAP + tap] : 0.f;
  wb[i] = f2bf(v);
}

// ---------------- weight repack: deconv  w[CI][CO][4][4] fp32 -> frags/class
// layout: [cls][tap][kc][ntall][lane][8]
template<int CI, int CO, int NTALL>
__global__ void repack_deconv_w(const float* __restrict__ w,
                                unsigned short* __restrict__ wb) {
  const int KC = CI / 16;
  const int total = 16 * KC * NTALL * 512;
  int i = blockIdx.x * 256 + threadIdx.x;
  if (i >= total) return;
  int j = i & 7, lane = (i >> 3) & 63, t2 = i >> 9;
  int nt = t2 % NTALL; t2 /= NTALL;
  int kc = t2 % KC; t2 /= KC;
  int tap = t2 & 3, cls = t2 >> 2;
  int a = cls >> 1, b = cls & 1, ti = tap >> 1, tj = tap & 1;
  int kh = 2 * ti + 1 - a, kw = 2 * tj + 1 - b;
  int co = nt * 32 + (lane & 31);
  int ci = kc * 16 + (lane >> 5) * 8 + j;
  wb[i] = f2bf(w[((ci * CO + co) * 4 + kh) * 4 + kw]);
}

// ---------------- weight repack: conv4 16x16 frags  dw3[3][128][3][3]
__global__ void repack_conv4_w(const float* __restrict__ w,
                               unsigned short* __restrict__ wb) {
  const int total = 9 * 4 * 512;
  int i = blockIdx.x * 256 + threadIdx.x;
  if (i >= total) return;
  int j = i & 7, lane = (i >> 3) & 63, tk = i >> 9;
  int kc = tk & 3, t = tk >> 2;
  int co = lane & 15;
  int ci = kc * 32 + (lane >> 4) * 8 + j;
  float v = (co < 3) ? w[(co * 128 + ci) * 9 + t] : 0.f;
  wb[i] = f2bf(v);
}

// ---------------- weight repack: conv1  ew1[128][3][4][4] -> wc1[tap*128+co] fp32
__global__ void repack_conv1_w(const float* __restrict__ w,
                               float* __restrict__ wc1) {
  int i = blockIdx.x * 256 + threadIdx.x;   // 6144
  if (i >= 6144) return;
  int tap = i >> 7, co = i & 127;
  wc1[i] = w[co * 48 + tap];
}

// ---------------- codebook repack -> bf16 B-frags [tile16][kc4][lane64][8]
__global__ void repack_cb(const float* __restrict__ cb,
                          unsigned short* __restrict__ cbf) {
  int i = blockIdx.x * 256 + threadIdx.x;   // 32768
  int j = i & 7, lane = (i >> 3) & 63;
  int kc = (i >> 9) & 3, tile = i >> 11;
  int code = tile * 32 + (lane & 31);
  int d = kc * 16 + (lane >> 5) * 8 + j;
  cbf[i] = f2bf(cb[code * 64 + d]);
}
__global__ void cnorm_k(const float* __restrict__ cb, float* __restrict__ cn) {
  int k = blockIdx.x * 256 + threadIdx.x;
  if (k >= 512) return;
  const float4* r = (const float4*)(cb + k * 64);
  float s = 0.f;
  #pragma unroll
  for (int q = 0; q < 16; ++q) {
    float4 v = r[q];
    s = fmaf(v.x, v.x, s); s = fmaf(v.y, v.y, s);
    s = fmaf(v.z, v.z, s); s = fmaf(v.w, v.w, s);
  }
  cn[k] = s;
}

// ---------------- conv1 v2: x NCHW fp32 [64,3,128,128] -> h1 NHWC bf16
__global__ __launch_bounds__(256, 4) void conv1_k(
    const float* __restrict__ x, const float* __restrict__ wc1,
    const float* __restrict__ bias, unsigned short* __restrict__ out) {
  __shared__ float swc[6144];          // [tap][co] 24 KB
  __shared__ float sx[3 * 10 * 132];   // [ci][r][c] 15.8 KB
  int tid = threadIdx.x;
  int n = blockIdx.x >> 4, ohq = blockIdx.x & 15;
  #pragma unroll
  for (int q = 0; q < 6; ++q) {
    int i = (q * 256 + tid) * 4;
    *(float4*)&swc[i] = *(const float4*)&wc1[i];
  }
  int ihb = 8 * ohq - 1;
  for (int i = tid; i < 3960; i += 256) {
    int ci = i / 1320, rem = i - ci * 1320;
    int r = rem / 132, c = rem - r * 132;
    int ih = ihb + r, iw = c - 1;
    float v = 0.f;
    if ((unsigned)ih < 128u && (unsigned)iw < 128u)
      v = x[(n * 3 + ci) * 16384 + ih * 128 + iw];
    sx[i] = v;
  }
  __syncthreads();
  int ow = tid >> 2, cg = tid & 3;
  #pragma unroll
  for (int cob = 0; cob < 2; ++cob) {
    int co0 = cob * 64 + cg * 16;
    float4 acc[4][4];
    float4 bq[4];
    #pragma unroll
    for (int q = 0; q < 4; ++q) bq[q] = *(const float4*)&bias[co0 + q * 4];
    #pragma unroll
    for (int o = 0; o < 4; ++o)
      #pragma unroll
      for (int q = 0; q < 4; ++q) acc[o][q] = bq[q];
    for (int ci = 0; ci < 3; ++ci)
      for (int kh = 0; kh < 4; ++kh) {
        #pragma unroll
        for (int kw = 0; kw < 4; ++kw) {
          int tap = ci * 16 + kh * 4 + kw;
          const float* wp = &swc[tap * 128 + co0];
          float4 w0 = *(const float4*)(wp);
          float4 w1 = *(const float4*)(wp + 4);
          float4 w2 = *(const float4*)(wp + 8);
          float4 w3 = *(const float4*)(wp + 12);
          const float* xp = &sx[ci * 1320 + kh * 132 + 2 * ow + kw];
          #pragma unroll
          for (int o = 0; o < 4; ++o) {
            float xv = xp[o * 264];
            acc[o][0].x = fmaf(xv, w0.x, acc[o][0].x);
            acc[o][0].y = fmaf(xv, w0.y, acc[o][0].y);
            acc[o][0].z = fmaf(xv, w0.z, acc[o][0].z);
            acc[o][0].w = fmaf(xv, w0.w, acc[o][0].w);
            acc[o][1].x = fmaf(xv, w1.x, acc[o][1].x);
            acc[o][1].y = fmaf(xv, w1.y, acc[o][1].y);
            acc[o][1].z = fmaf(xv, w1.z, acc[o][1].z);
            acc[o][1].w = fmaf(xv, w1.w, acc[o][1].w);
            acc[o][2].x = fmaf(xv, w2.x, acc[o][2].x);
            acc[o][2].y = fmaf(xv, w2.y, acc[o][2].y);
            acc[o][2].z = fmaf(xv, w2.z, acc[o][2].z);
            acc[o][2].w = fmaf(xv, w2.w, acc[o][2].w);
            acc[o][3].x = fmaf(xv, w3.x, acc[o][3].x);
            acc[o][3].y = fmaf(xv, w3.y, acc[o][3].y);
            acc[o][3].z = fmaf(xv, w3.z, acc[o][3].z);
            acc[o][3].w = fmaf(xv, w3.w, acc[o][3].w);
          }
        }
      }
    #pragma unroll
    for (int o = 0; o < 4; ++o) {
      int oh = ohq * 4 + o;
      unsigned short* op = out + ((size_t)(n * 64 + oh) * 64 + ow) * 128 + co0;
      uint4 u0, u1;
      u0.x = pack2bf(fmaxf(acc[o][0].x, 0.f), fmaxf(acc[o][0].y, 0.f));
      u0.y = pack2bf(fmaxf(acc[o][0].z, 0.f), fmaxf(acc[o][0].w, 0.f));
      u0.z = pack2bf(fmaxf(acc[o][1].x, 0.f), fmaxf(acc[o][1].y, 0.f));
      u0.w = pack2bf(fmaxf(acc[o][1].z, 0.f), fmaxf(acc[o][1].w, 0.f));
      u1.x = pack2bf(fmaxf(acc[o][2].x, 0.f), fmaxf(acc[o][2].y, 0.f));
      u1.y = pack2bf(fmaxf(acc[o][2].z, 0.f), fmaxf(acc[o][2].w, 0.f));
      u1.z = pack2bf(fmaxf(acc[o][3].x, 0.f), fmaxf(acc[o][3].y, 0.f));
      u1.w = pack2bf(fmaxf(acc[o][3].z, 0.f), fmaxf(acc[o][3].w, 0.f));
      *(uint4*)(op) = u0;
      *(uint4*)(op + 8) = u1;
    }
  }
}

// ---------------- generic MFMA conv (conv2/conv3), r9 form (S=2, 4 blk/CU)
template<int CI, int CO, int NTALL, int NT, int S, int IH, int IW, int OH, int OW,
         int NTAP, int KW, int STRIDE, bool DECONV, bool RELU, bool F32OUT>
__global__ __launch_bounds__(256, 4) void mconv_k(
    const unsigned short* __restrict__ in, const unsigned short* __restrict__ wb,
    const float* __restrict__ bias, void* __restrict__ outv,
    const unsigned short* __restrict__ zeropg) {
  const int KC = CI / 16;
  const int TSZ = KC * NT * 512;
  const int STG = KC * NT / 4;
  __shared__ unsigned short sB[2][TSZ];
  int tid = threadIdx.x, lane = tid & 63, wv = tid >> 6;
  int m0 = blockIdx.x * (128 * S) + wv * (32 * S);
  int cls = DECONV ? blockIdx.y : 0;
  int cog = blockIdx.z;
  int ca = cls >> 1, cb2 = cls & 1;
  int khalf = lane >> 5;
  int n_[S], oh_[S], ow_[S];
  #pragma unroll
  for (int s = 0; s < S; ++s) {
    int mm = m0 + s * 32 + (lane & 31);
    n_[s] = mm / (OH * OW);
    int rem = mm % (OH * OW);
    oh_[s] = rem / OW; ow_[s] = rem % OW;
  }
  f32x16 acc[S][NT];
  #pragma unroll
  for (int s = 0; s < S; ++s)
    #pragma unroll
    for (int t = 0; t < NT; ++t)
      #pragma unroll
      for (int e = 0; e < 16; ++e) acc[s][t][e] = 0.f;

  const unsigned short* wcls = wb + (size_t)cls * NTAP * KC * NTALL * 512;
  uint4 st[STG];
  #pragma unroll
  for (int q = 0; q < STG; ++q) {
    int i = q * 256 + tid;
    int kc = i / (NT * 64), r = i - kc * (NT * 64);
    st[q] = *(const uint4*)(wcls + (size_t)(kc * NTALL + cog * NT) * 512 + r * 8);
  }
  #pragma unroll
  for (int q = 0; q < STG; ++q) {
    int i = q * 256 + tid;
    *(uint4*)&sB[0][i * 8] = st[q];
  }
  __syncthreads();

  for (int t = 0; t < NTAP; ++t) {
    int cur = t & 1;
    if (t + 1 < NTAP) {
      const unsigned short* wt = wcls + (size_t)(t + 1) * KC * NTALL * 512;
      #pragma unroll
      for (int q = 0; q < STG; ++q) {
        int i = q * 256 + tid;
        int kc = i / (NT * 64), r = i - kc * (NT * 64);
        st[q] = *(const uint4*)(wt + (size_t)(kc * NTALL + cog * NT) * 512 + r * 8);
      }
    }
    const unsigned short* ap[S];
    #pragma unroll
    for (int s = 0; s < S; ++s) {
      int ih, iw;
      if (DECONV) { ih = oh_[s] + ca - (t >> 1); iw = ow_[s] + cb2 - (t & 1); }
      else        { ih = STRIDE * oh_[s] - 1 + t / KW; iw = STRIDE * ow_[s] - 1 + t % KW; }
      bool valid = ((unsigned)ih < (unsigned)IH) && ((unsigned)iw < (unsigned)IW);
      ap[s] = valid ? (in + ((size_t)(n_[s] * IH + ih) * IW + iw) * CI + khalf * 8)
                    : (zeropg + khalf * 8);
    }
    #pragma unroll
    for (int kc = 0; kc < KC; ++kc) {
      short8 a[S];
      #pragma unroll
      for (int s = 0; s < S; ++s) a[s] = *(const short8*)(ap[s] + kc * 16);
      #pragma unroll
      for (int nt = 0; nt < NT; ++nt) {
        short8 b = *(const short8*)&sB[cur][(kc * NT + nt) * 512 + lane * 8];
        #pragma unroll
        for (int s = 0; s < S; ++s)
          acc[s][nt] = __builtin_amdgcn_mfma_f32_32x32x16_bf16(a[s], b, acc[s][nt], 0, 0, 0);
      }
    }
    if (t + 1 < NTAP) {
      #pragma unroll
      for (int q = 0; q < STG; ++q) {
        int i = q * 256 + tid;
        *(uint4*)&sB[cur ^ 1][i * 8] = st[q];
      }
    }
    __syncthreads();
  }

  int col = lane & 31;
  #pragma unroll
  for (int s = 0; s < S; ++s)
    #pragma unroll
    for (int nt = 0; nt < NT; ++nt) {
      int co = (cog * NT + nt) * 32 + col;
      float bv = bias[co];
      #pragma unroll
      for (int r = 0; r < 16; ++r) {
        int mrow = (r & 3) + 8 * (r >> 2) + 4 * khalf;
        int mp = m0 + s * 32 + mrow;
        int n2 = mp / (OH * OW), r2 = mp % (OH * OW);
        int oh2 = r2 / OW, ow2 = r2 % OW;
        float v = acc[s][nt][r] + bv;
        if (RELU) v = fmaxf(v, 0.f);
        size_t idx;
        if (DECONV)
          idx = ((size_t)(n2 * (2 * OH) + 2 * oh2 + ca) * (2 * OW) + 2 * ow2 + cb2) * CO + co;
        else
          idx = ((size_t)(n2 * OH + oh2) * OW + ow2) * CO + co;
        if (F32OUT) ((float*)outv)[idx] = v;
        else        ((unsigned short*)outv)[idx] = f2bf(v);
      }
    }
}

// ---------------- dconv_k: parity-deconv, whole per-(cls,cog) B in LDS,
// kc-OUTER tap-INNER for A-locality (per-kc footprint ~18KB -> L2-resident).
// HW = input spatial dim; output = 2*HW. NT=2, S=2.
template<int CI, int CO, int NTALL, int NT, int S, int HW>
__global__ __launch_bounds__(256, 2) void dconv_k(
    const unsigned short* __restrict__ in, const unsigned short* __restrict__ wb,
    const float* __restrict__ bias, unsigned short* __restrict__ out,
    const unsigned short* __restrict__ zeropg) {
  const int KC = CI / 16;
  const int TOT = 4 * KC * NT * 512;     // shorts: all 4 taps of this (cls,cog)
  const int NU  = TOT / (8 * 256);       // uint4 per thread for staging
  const int CHU = NT * 64;               // uint4 per (tap,kc) chunk
  __shared__ unsigned short sB[TOT];
  int tid = threadIdx.x, lane = tid & 63, wv = tid >> 6;
  int m0 = blockIdx.x * (128 * S) + wv * (32 * S);
  int cls = blockIdx.y, cog = blockIdx.z;
  int ca = cls >> 1, cb2 = cls & 1;
  int khalf = lane >> 5;
  int n_[S], oh_[S], ow_[S];
  #pragma unroll
  for (int s = 0; s < S; ++s) {
    int mm = m0 + s * 32 + (lane & 31);
    n_[s] = mm / (HW * HW);
    int rem = mm % (HW * HW);
    oh_[s] = rem / HW; ow_[s] = rem % HW;
  }
  // stage all B for this (cls,cog); src layout [cls][tap][kc][NTALL][lane][8]
  const unsigned short* wcls = wb + (size_t)cls * 4 * KC * NTALL * 512;
  #pragma unroll
  for (int q = 0; q < NU; ++q) {
    int g = q * 256 + tid;
    int chunk = g / CHU, within = g - chunk * CHU;   // chunk = tap*KC+kc
    *(uint4*)&sB[(chunk * NT * 64 + within) * 8] =
        *(const uint4*)(wcls + ((size_t)chunk * NTALL + cog * NT) * 512 + within * 8);
  }
  // A base pointers per (tap,s) -- kc-invariant
  const unsigned short* ap[4][S];
  #pragma unroll
  for (int t = 0; t < 4; ++t)
    #pragma unroll
    for (int s = 0; s < S; ++s) {
      int ih = oh_[s] + ca - (t >> 1), iw = ow_[s] + cb2 - (t & 1);
      bool valid = ((unsigned)ih < (unsigned)HW) && ((unsigned)iw < (unsigned)HW);
      ap[t][s] = valid ? (in + ((size_t)(n_[s] * HW + ih) * HW + iw) * CI + khalf * 8)
                       : (zeropg + khalf * 8);
    }
  f32x16 acc[S][NT];
  #pragma unroll
  for (int s = 0; s < S; ++s)
    #pragma unroll
    for (int t = 0; t < NT; ++t)
      #pragma unroll
      for (int e = 0; e < 16; ++e) acc[s][t][e] = 0.f;
  __syncthreads();

  #pragma unroll
  for (int kc = 0; kc < KC; ++kc) {
    #pragma unroll
    for (int t = 0; t < 4; ++t) {
      short8 a[S];
      #pragma unroll
      for (int s = 0; s < S; ++s) a[s] = *(const short8*)(ap[t][s] + kc * 16);
      #pragma unroll
      for (int nt = 0; nt < NT; ++nt) {
        short8 b = *(const short8*)&sB[((t * KC + kc) * NT + nt) * 512 + lane * 8];
        #pragma unroll
        for (int s = 0; s < S; ++s)
          acc[s][nt] = __builtin_amdgcn_mfma_f32_32x32x16_bf16(a[s], b, acc[s][nt], 0, 0, 0);
      }
    }
  }

  int col = lane & 31;
  #pragma unroll
  for (int s = 0; s < S; ++s)
    #pragma unroll
    for (int nt = 0; nt < NT; ++nt) {
      int co = (cog * NT + nt) * 32 + col;
      float bv = bias[co];
      #pragma unroll
      for (int r = 0; r < 16; ++r) {
        int mrow = (r & 3) + 8 * (r >> 2) + 4 * khalf;
        int mp = m0 + s * 32 + mrow;
        int n2 = mp / (HW * HW), r2 = mp % (HW * HW);
        int oh2 = r2 / HW, ow2 = r2 % HW;
        float v = fmaxf(acc[s][nt][r] + bv, 0.f);
        size_t idx = ((size_t)(n2 * (2 * HW) + 2 * oh2 + ca) * (2 * HW) + 2 * ow2 + cb2) * CO + co;
        out[idx] = f2bf(v);
      }
    }
}

// ---------------- VQ via MFMA, codebook frags staged in LDS (2 phases x 32KB)
__global__ __launch_bounds__(256, 2) void vq2_k(
    const float* __restrict__ ze, const float* __restrict__ cb,
    const unsigned short* __restrict__ cbf, const float* __restrict__ cnorm,
    unsigned short* __restrict__ zq, float* __restrict__ acc_loss) {
  __shared__ unsigned short sC[16384];   // 8 tiles of B-frags (32 KB)
  __shared__ int s_idx[4][32];
  int tid = threadIdx.x, lane = tid & 63, wv = tid >> 6;
  int m0 = blockIdx.x * 128 + wv * 32;
  int col = lane & 31, khalf = lane >> 5;
  const float* zrow = ze + (size_t)(m0 + col) * 64 + khalf * 8;
  short8 af[4];
  #pragma unroll
  for (int kc = 0; kc < 4; ++kc) {
    float4 a = *(const float4*)(zrow + kc * 16);
    float4 b = *(const float4*)(zrow + kc * 16 + 4);
    short8 f;
    f[0] = (short)f2bf(a.x); f[1] = (short)f2bf(a.y);
    f[2] = (short)f2bf(a.z); f[3] = (short)f2bf(a.w);
    f[4] = (short)f2bf(b.x); f[5] = (short)f2bf(b.y);
    f[6] = (short)f2bf(b.z); f[7] = (short)f2bf(b.w);
    af[kc] = f;
  }
  float best[16]; int bidx[16];
  #pragma unroll
  for (int r = 0; r < 16; ++r) { best[r] = 3.4e38f; bidx[r] = 0; }
  for (int half = 0; half < 2; ++half) {
    #pragma unroll
    for (int q = 0; q < 8; ++q) {
      int i = q * 256 + tid;
      *(uint4*)&sC[i * 8] = *(const uint4*)(cbf + half * 16384 + i * 8);
    }
    __syncthreads();
    #pragma unroll
    for (int t8 = 0; t8 < 8; ++t8) {
      int tt = half * 8 + t8;
      f32x16 acc;
      #pragma unroll
      for (int e = 0; e < 16; ++e) acc[e] = 0.f;
      #pragma unroll
      for (int kc = 0; kc < 4; ++kc) {
        short8 bf_ = *(const short8*)&sC[(t8 * 4 + kc) * 512 + lane * 8];
        acc = __builtin_amdgcn_mfma_f32_32x32x16_bf16(af[kc], bf_, acc, 0, 0, 0);
      }
      float cn = cnorm[tt * 32 + col];
      int code = tt * 32 + col;
      #pragma unroll
      for (int r = 0; r < 16; ++r) {
        float d = fmaf(-2.f, acc[r], cn);
        if (d < best[r]) { best[r] = d; bidx[r] = code; }
      }
    }
    __syncthreads();
  }
  #pragma unroll
  for (int off = 1; off < 32; off <<= 1) {
    #pragma unroll
    for (int r = 0; r < 16; ++r) {
      float ob = __shfl_xor(best[r], off, 64);
      int   oi = __shfl_xor(bidx[r], off, 64);
      if (ob < best[r]) { best[r] = ob; bidx[r] = oi; }
    }
  }
  if (col == 0) {
    #pragma unroll
    for (int r = 0; r < 16; ++r)
      s_idx[wv][(r & 3) + 8 * (r >> 2) + 4 * khalf] = bidx[r];
  }
  __syncthreads();
  int row = lane >> 1, half2 = lane & 1;
  int m = m0 + row;
  int idx = s_idx[wv][row];
  const float4* crow = (const float4*)(cb + idx * 64 + half2 * 32);
  const float4* zp = (const float4*)(ze + (size_t)m * 64 + half2 * 32);
  uint2* zqp = (uint2*)(zq + (size_t)m * 64 + half2 * 32);
  float lsum = 0.f;
  #pragma unroll
  for (int q = 0; q < 8; ++q) {
    float4 c4 = crow[q];
    float4 z4 = zp[q];
    uint2 u; u.x = pack2bf(c4.x, c4.y); u.y = pack2bf(c4.z, c4.w);
    zqp[q] = u;
    float d;
    d = z4.x - c4.x; lsum = fmaf(d, d, lsum);
    d = z4.y - c4.y; lsum = fmaf(d, d, lsum);
    d = z4.z - c4.z; lsum = fmaf(d, d, lsum);
    d = z4.w - c4.w; lsum = fmaf(d, d, lsum);
  }
  #pragma unroll
  for (int off = 32; off > 0; off >>= 1) lsum += __shfl_down(lsum, off, 64);
  if (lane == 0) atomicAdd(acc_loss, lsum);
}

// ---------------- conv4: d2 NHWC bf16 -> x_recon NCHW fp32 (+recon loss)
// 16x16x32 MFMA, N=16; kc-OUTER tap-INNER (per-kc footprint 1/4, dw in L1).
__global__ __launch_bounds__(256, 3) void conv4_k(
    const unsigned short* __restrict__ in, const unsigned short* __restrict__ wb,
    const float* __restrict__ bias, const float* __restrict__ x,
    float* __restrict__ out, float* __restrict__ acc_loss,
    const unsigned short* __restrict__ zeropg) {
  __shared__ unsigned short sW[18432];   // 9 taps x 4 kc x 512 (36 KB)
  int tid = threadIdx.x, lane = tid & 63, wv = tid >> 6;
  #pragma unroll
  for (int q = 0; q < 9; ++q) {
    int i = q * 256 + tid;
    *(uint4*)&sW[i * 8] = *(const uint4*)(wb + i * 8);
  }
  int m0 = blockIdx.x * 256 + wv * 64;
  int quad = lane >> 4, mloc = lane & 15;
  int n_[4], oh_[4], ow_[4];
  #pragma unroll
  for (int s = 0; s < 4; ++s) {
    int mm = m0 + s * 16 + mloc;
    n_[s] = mm >> 14;
    int rem = mm & 16383;
    oh_[s] = rem >> 7; ow_[s] = rem & 127;
  }
  // tap base pointers (kc-invariant): 9 x 4
  const unsigned short* ap[9][4];
  #pragma unroll
  for (int t = 0; t < 9; ++t) {
    int dh = t / 3 - 1, dw = t % 3 - 1;
    #pragma unroll
    for (int s = 0; s < 4; ++s) {
      int ih = oh_[s] + dh, iw = ow_[s] + dw;
      bool valid = ((unsigned)ih < 128u) && ((unsigned)iw < 128u);
      ap[t][s] = valid ? (in + ((size_t)(n_[s] * 128 + ih) * 128 + iw) * 128 + quad * 8)
                       : (zeropg + quad * 8);
    }
  }
  f32x4 acc[4];
  #pragma unroll
  for (int s = 0; s < 4; ++s)
    #pragma unroll
    for (int e = 0; e < 4; ++e) acc[s][e] = 0.f;
  __syncthreads();
  #pragma unroll
  for (int kc = 0; kc < 4; ++kc) {
    #pragma unroll
    for (int t = 0; t < 9; ++t) {
      short8 bf_ = *(const short8*)&sW[(t * 4 + kc) * 512 + lane * 8];
      #pragma unroll
      for (int s = 0; s < 4; ++s) {
        short8 a = *(const short8*)(ap[t][s] + kc * 32);
        acc[s] = __builtin_amdgcn_mfma_f32_16x16x32_bf16(a, bf_, acc[s], 0, 0, 0);
      }
    }
  }
  int co = lane & 15;
  float bv = (co < 3) ? bias[co] : 0.f;
  float lsum = 0.f;
  #pragma unroll
  for (int s = 0; s < 4; ++s)
    #pragma unroll
    for (int r = 0; r < 4; ++r) {
      int m = m0 + s * 16 + quad * 4 + r;
      if (co < 3) {
        float v = acc[s][r] + bv;
        int n2 = m >> 14, r2 = m & 16383;
        int gi = (n2 * 3 + co) * 16384 + r2;
        out[gi] = v;
        float d = v - x[gi];
        lsum = fmaf(d, d, lsum);
      }
    }
  #pragma unroll
  for (int off = 32; off > 0; off >>= 1) lsum += __shfl_down(lsum, off, 64);
  if (lane == 0) atomicAdd(acc_loss, lsum);
}

// ---------------- finalize losses
__global__ void finalize_k(const float* __restrict__ accv, float* __restrict__ out) {
  if (threadIdx.x == 0 && blockIdx.x == 0) {
    float recon = accv[0] / 3145728.0f;
    float vq = 1.25f * accv[1] / 4194304.0f;
    out[3145728] = recon + vq;
    out[3145729] = recon;
    out[3145730] = vq;
  }
}

extern "C" void kernel_launch(void* const* d_in, const int* in_sizes, int n_in,
                              void* d_out, int out_size, void* d_ws, size_t ws_size,
                              hipStream_t stream) {
  const float* x   = (const float*)d_in[0];
  const float* ew1 = (const float*)d_in[1];
  const float* eb1 = (const float*)d_in[2];
  const float* ew2 = (const float*)d_in[3];
  const float* eb2 = (const float*)d_in[4];
  const float* ew3 = (const float*)d_in[5];
  const float* eb3 = (const float*)d_in[6];
  const float* cb  = (const float*)d_in[7];
  const float* dw1 = (const float*)d_in[8];
  const float* db1 = (const float*)d_in[9];
  const float* dw2 = (const float*)d_in[10];
  const float* db2 = (const float*)d_in[11];
  const float* dw3 = (const float*)d_in[12];
  const float* db3 = (const float*)d_in[13];
  float* out = (float*)d_out;

  char* ws = (char*)d_ws;
  float* acc = (float*)ws;                               // [0]=recon ss, [1]=vq ss
  unsigned short* zeropg = (unsigned short*)(ws + 256);  // 512B zero page
  char* p = ws + 1024;
  unsigned short* wb2  = (unsigned short*)p; p += 524288;  // conv2 16*8*4*512*2
  unsigned short* wb3  = (unsigned short*)p; p += 147456;  // conv3  9*8*2*512*2
  unsigned short* wb4  = (unsigned short*)p; p += 36864;   // conv4 9*4*512*2
  unsigned short* wbd1 = (unsigned short*)p; p += 262144;  // dc1 4*4*4*4*512*2
  unsigned short* wbd2 = (unsigned short*)p; p += 524288;  // dc2 4*4*8*4*512*2
  unsigned short* cbf  = (unsigned short*)p; p += 65536;   // cb frags
  float*          cnrm = (float*)p;          p += 2048;
  float*          wc1  = (float*)p;          p += 24576;   // conv1 [tap][co] fp32
  size_t fixed = (size_t)(p - ws);

  // full-batch intermediates
  unsigned short* h1 = (unsigned short*)p; p += 67108864ull;  // h1 / d1 slot
  unsigned short* h2 = (unsigned short*)p; p += 16777216ull;
  float*          ze = (float*)p;          p += 16777216ull;
  unsigned short* zq = (unsigned short*)p; p += 8388608ull;
  unsigned short* d2 = (unsigned short*)p;
  size_t base = fixed + 67108864ull + 16777216ull + 16777216ull + 8388608ull;
  int CD = 64;
  while (CD > 1 && base + (size_t)CD * 4194304ull > ws_size) CD >>= 1;

  hipMemsetAsync(ws, 0, 1024, stream);   // loss accumulators + zero page
  repack_conv_w<128, 16, 4><<<(16 * 8 * 4 * 512 + 255) / 256, 256, 0, stream>>>(ew2, wb2, 128);
  repack_conv_w<128, 9, 2><<<(9 * 8 * 2 * 512 + 255) / 256, 256, 0, stream>>>(ew3, wb3, 64);
  repack_conv4_w<<<(9 * 4 * 512 + 255) / 256, 256, 0, stream>>>(dw3, wb4);
  repack_deconv_w<64, 128, 4><<<(16 * 4 * 4 * 512 + 255) / 256, 256, 0, stream>>>(dw1, wbd1);
  repack_deconv_w<128, 128, 4><<<(16 * 8 * 4 * 512 + 255) / 256, 256, 0, stream>>>(dw2, wbd2);
  repack_cb<<<128, 256, 0, stream>>>(cb, cbf);
  cnorm_k<<<2, 256, 0, stream>>>(cb, cnrm);
  repack_conv1_w<<<24, 256, 0, stream>>>(ew1, wc1);

  // ---- encoder, full batch ----
  conv1_k<<<1024, 256, 0, stream>>>(x, wc1, eb1, h1);
  // conv2: M=65536, block M=256 (S=2) -> 256 x, cog z=2 (512 blocks)
  mconv_k<128, 128, 4, 2, 2, 64, 64, 32, 32, 16, 4, 2, false, true, false>
      <<<dim3(256, 1, 2), 256, 0, stream>>>(h1, wb2, eb2, h2, zeropg);
  // conv3: M=65536, block M=256 (S=2) -> 256 x, NT=2 covers CO=64
  mconv_k<128, 64, 2, 2, 2, 32, 32, 32, 32, 9, 3, 1, false, false, true>
      <<<dim3(256, 1, 1), 256, 0, stream>>>(h2, wb3, eb3, ze, zeropg);
  vq2_k<<<512, 256, 0, stream>>>(ze, cb, cbf, cnrm, zq, acc + 1);
  // dc1: M=65536, block M=256 -> 256 x, 4 cls, cog 2 (2048 blocks), B 32KB LDS
  dconv_k<64, 128, 4, 2, 2, 32>
      <<<dim3(256, 4, 2), 256, 0, stream>>>(zq, wbd1, db1, h1, zeropg);

  // ---- decoder, full batch ----
  for (int n0 = 0; n0 < 64; n0 += CD) {
    const unsigned short* d1c = h1 + (size_t)n0 * 524288;   // 64*64*128
    // dc2: M=CD*4096, block M=256 -> CD*16 x, 4 cls, cog 2 (CD=64: 8192), B 64KB LDS
    dconv_k<128, 128, 4, 2, 2, 64>
        <<<dim3(CD * 16, 4, 2), 256, 0, stream>>>(d1c, wbd2, db2, d2, zeropg);
    conv4_k<<<CD * 64, 256, 0, stream>>>(d2, wb4, db3, x + (size_t)n0 * 49152,
                                         out + (size_t)n0 * 49152, acc, zeropg);
  }
  finalize_k<<<1, 64, 0, stream>>>(acc, out);
}

// Round 11
// 997.963 us; speedup vs baseline: 1.1408x; 1.1408x over previous
//
#include <hip/hip_runtime.h>
#include <hip/hip_bf16.h>

// ---- VQ-VAE forward, round 11 ---------------------------------------------
// r10 post-mortem: kc-outer dconv regressed (FETCH up). Model: dc1/dc2 excess
// FETCH = 8x cls*cog A-replication across blocks that land on DIFFERENT XCDs
// (rr mapping, xcd ~ blockIdx%8) far apart in dispatch order -> per-XCD L2
// misses. r11: revert to r9 mconv bodies + XCD-aware 1-D grid swizzle:
// i = a*64 + b*8 + c -> tile = a*8+c, sub(cls,cog) = b. All 8 replicas of a
// tile are within one 64-index window AND congruent mod 8 (same XCD) -> one
// HBM fetch serves 8. conv2 (2 cog, window 16) and conv4 (halo-sharing row
// groups) swizzled likewise. Pure index math; worst case neutral.
// Layouts (HW-verified): 32x32x16_bf16 A[m=lane&31][k=(lane>>5)*8+j],
//   D: col=lane&31, row=(reg&3)+8*(reg>>2)+4*(lane>>5).
// 16x16x32_bf16 A[m=lane&15][k=(lane>>4)*8+j], D: col=lane&15,
//   row=(lane>>4)*4+reg.
// Deconv k4s2p1 parity (a,b): out(2q+a,2r+b) += in(q+a-i, r+b-j)*
//   w[ci][co][2i+1-a][2j+1-b]  (verified r2-r10).

typedef __attribute__((ext_vector_type(8))) short short8;
typedef __attribute__((ext_vector_type(16))) float f32x16;
typedef __attribute__((ext_vector_type(4))) float f32x4;

__device__ __forceinline__ unsigned short f2bf(float f) {
  union { __hip_bfloat16 b; unsigned short u; } cv;
  cv.b = __float2bfloat16(f);
  return cv.u;
}
__device__ __forceinline__ unsigned pack2bf(float a, float b) {
  return (unsigned)f2bf(a) | ((unsigned)f2bf(b) << 16);
}

// ---------------- weight repack: conv layers  w[CO][CI][NTAP] fp32 -> frags
// layout: [tap][kc][ntall][lane][8]
template<int CI, int NTAP, int NTALL>
__global__ void repack_conv_w(const float* __restrict__ w,
                              unsigned short* __restrict__ wb, int co_real) {
  const int KC = CI / 16;
  const int total = NTAP * KC * NTALL * 512;
  int i = blockIdx.x * 256 + threadIdx.x;
  if (i >= total) return;
  int j = i & 7, lane = (i >> 3) & 63, t2 = i >> 9;
  int nt = t2 % NTALL; t2 /= NTALL;
  int kc = t2 % KC; int tap = t2 / KC;
  int co = nt * 32 + (lane & 31);
  int ci = kc * 16 + (lane >> 5) * 8 + j;
  float v = (co < co_real) ? w[(co * CI + ci) * NTAP + tap] : 0.f;
  wb[i] = f2bf(v);
}

// ---------------- weight repack: deconv  w[CI][CO][4][4] fp32 -> frags/class
// layout: [cls][tap][kc][ntall][lane][8]
template<int CI, int CO, int NTALL>
__global__ void repack_deconv_w(const float* __restrict__ w,
                                unsigned short* __restrict__ wb) {
  const int KC = CI / 16;
  const int total = 16 * KC * NTALL * 512;
  int i = blockIdx.x * 256 + threadIdx.x;
  if (i >= total) return;
  int j = i & 7, lane = (i >> 3) & 63, t2 = i >> 9;
  int nt = t2 % NTALL; t2 /= NTALL;
  int kc = t2 % KC; t2 /= KC;
  int tap = t2 & 3, cls = t2 >> 2;
  int a = cls >> 1, b = cls & 1, ti = tap >> 1, tj = tap & 1;
  int kh = 2 * ti + 1 - a, kw = 2 * tj + 1 - b;
  int co = nt * 32 + (lane & 31);
  int ci = kc * 16 + (lane >> 5) * 8 + j;
  wb[i] = f2bf(w[((ci * CO + co) * 4 + kh) * 4 + kw]);
}

// ---------------- weight repack: conv4 16x16 frags  dw3[3][128][3][3]
__global__ void repack_conv4_w(const float* __restrict__ w,
                               unsigned short* __restrict__ wb) {
  const int total = 9 * 4 * 512;
  int i = blockIdx.x * 256 + threadIdx.x;
  if (i >= total) return;
  int j = i & 7, lane = (i >> 3) & 63, tk = i >> 9;
  int kc = tk & 3, t = tk >> 2;
  int co = lane & 15;
  int ci = kc * 32 + (lane >> 4) * 8 + j;
  float v = (co < 3) ? w[(co * 128 + ci) * 9 + t] : 0.f;
  wb[i] = f2bf(v);
}

// ---------------- weight repack: conv1  ew1[128][3][4][4] -> wc1[tap*128+co] fp32
__global__ void repack_conv1_w(const float* __restrict__ w,
                               float* __restrict__ wc1) {
  int i = blockIdx.x * 256 + threadIdx.x;   // 6144
  if (i >= 6144) return;
  int tap = i >> 7, co = i & 127;
  wc1[i] = w[co * 48 + tap];
}

// ---------------- codebook repack -> bf16 B-frags [tile16][kc4][lane64][8]
__global__ void repack_cb(const float* __restrict__ cb,
                          unsigned short* __restrict__ cbf) {
  int i = blockIdx.x * 256 + threadIdx.x;   // 32768
  int j = i & 7, lane = (i >> 3) & 63;
  int kc = (i >> 9) & 3, tile = i >> 11;
  int code = tile * 32 + (lane & 31);
  int d = kc * 16 + (lane >> 5) * 8 + j;
  cbf[i] = f2bf(cb[code * 64 + d]);
}
__global__ void cnorm_k(const float* __restrict__ cb, float* __restrict__ cn) {
  int k = blockIdx.x * 256 + threadIdx.x;
  if (k >= 512) return;
  const float4* r = (const float4*)(cb + k * 64);
  float s = 0.f;
  #pragma unroll
  for (int q = 0; q < 16; ++q) {
    float4 v = r[q];
    s = fmaf(v.x, v.x, s); s = fmaf(v.y, v.y, s);
    s = fmaf(v.z, v.z, s); s = fmaf(v.w, v.w, s);
  }
  cn[k] = s;
}

// ---------------- conv1 v2: x NCHW fp32 [64,3,128,128] -> h1 NHWC bf16
__global__ __launch_bounds__(256, 4) void conv1_k(
    const float* __restrict__ x, const float* __restrict__ wc1,
    const float* __restrict__ bias, unsigned short* __restrict__ out) {
  __shared__ float swc[6144];          // [tap][co] 24 KB
  __shared__ float sx[3 * 10 * 132];   // [ci][r][c] 15.8 KB
  int tid = threadIdx.x;
  int n = blockIdx.x >> 4, ohq = blockIdx.x & 15;
  #pragma unroll
  for (int q = 0; q < 6; ++q) {
    int i = (q * 256 + tid) * 4;
    *(float4*)&swc[i] = *(const float4*)&wc1[i];
  }
  int ihb = 8 * ohq - 1;
  for (int i = tid; i < 3960; i += 256) {
    int ci = i / 1320, rem = i - ci * 1320;
    int r = rem / 132, c = rem - r * 132;
    int ih = ihb + r, iw = c - 1;
    float v = 0.f;
    if ((unsigned)ih < 128u && (unsigned)iw < 128u)
      v = x[(n * 3 + ci) * 16384 + ih * 128 + iw];
    sx[i] = v;
  }
  __syncthreads();
  int ow = tid >> 2, cg = tid & 3;
  #pragma unroll
  for (int cob = 0; cob < 2; ++cob) {
    int co0 = cob * 64 + cg * 16;
    float4 acc[4][4];
    float4 bq[4];
    #pragma unroll
    for (int q = 0; q < 4; ++q) bq[q] = *(const float4*)&bias[co0 + q * 4];
    #pragma unroll
    for (int o = 0; o < 4; ++o)
      #pragma unroll
      for (int q = 0; q < 4; ++q) acc[o][q] = bq[q];
    for (int ci = 0; ci < 3; ++ci)
      for (int kh = 0; kh < 4; ++kh) {
        #pragma unroll
        for (int kw = 0; kw < 4; ++kw) {
          int tap = ci * 16 + kh * 4 + kw;
          const float* wp = &swc[tap * 128 + co0];
          float4 w0 = *(const float4*)(wp);
          float4 w1 = *(const float4*)(wp + 4);
          float4 w2 = *(const float4*)(wp + 8);
          float4 w3 = *(const float4*)(wp + 12);
          const float* xp = &sx[ci * 1320 + kh * 132 + 2 * ow + kw];
          #pragma unroll
          for (int o = 0; o < 4; ++o) {
            float xv = xp[o * 264];
            acc[o][0].x = fmaf(xv, w0.x, acc[o][0].x);
            acc[o][0].y = fmaf(xv, w0.y, acc[o][0].y);
            acc[o][0].z = fmaf(xv, w0.z, acc[o][0].z);
            acc[o][0].w = fmaf(xv, w0.w, acc[o][0].w);
            acc[o][1].x = fmaf(xv, w1.x, acc[o][1].x);
            acc[o][1].y = fmaf(xv, w1.y, acc[o][1].y);
            acc[o][1].z = fmaf(xv, w1.z, acc[o][1].z);
            acc[o][1].w = fmaf(xv, w1.w, acc[o][1].w);
            acc[o][2].x = fmaf(xv, w2.x, acc[o][2].x);
            acc[o][2].y = fmaf(xv, w2.y, acc[o][2].y);
            acc[o][2].z = fmaf(xv, w2.z, acc[o][2].z);
            acc[o][2].w = fmaf(xv, w2.w, acc[o][2].w);
            acc[o][3].x = fmaf(xv, w3.x, acc[o][3].x);
            acc[o][3].y = fmaf(xv, w3.y, acc[o][3].y);
            acc[o][3].z = fmaf(xv, w3.z, acc[o][3].z);
            acc[o][3].w = fmaf(xv, w3.w, acc[o][3].w);
          }
        }
      }
    #pragma unroll
    for (int o = 0; o < 4; ++o) {
      int oh = ohq * 4 + o;
      unsigned short* op = out + ((size_t)(n * 64 + oh) * 64 + ow) * 128 + co0;
      uint4 u0, u1;
      u0.x = pack2bf(fmaxf(acc[o][0].x, 0.f), fmaxf(acc[o][0].y, 0.f));
      u0.y = pack2bf(fmaxf(acc[o][0].z, 0.f), fmaxf(acc[o][0].w, 0.f));
      u0.z = pack2bf(fmaxf(acc[o][1].x, 0.f), fmaxf(acc[o][1].y, 0.f));
      u0.w = pack2bf(fmaxf(acc[o][1].z, 0.f), fmaxf(acc[o][1].w, 0.f));
      u1.x = pack2bf(fmaxf(acc[o][2].x, 0.f), fmaxf(acc[o][2].y, 0.f));
      u1.y = pack2bf(fmaxf(acc[o][2].z, 0.f), fmaxf(acc[o][2].w, 0.f));
      u1.z = pack2bf(fmaxf(acc[o][3].x, 0.f), fmaxf(acc[o][3].y, 0.f));
      u1.w = pack2bf(fmaxf(acc[o][3].z, 0.f), fmaxf(acc[o][3].w, 0.f));
      *(uint4*)(op) = u0;
      *(uint4*)(op + 8) = u1;
    }
  }
}

// ---------------- generic MFMA conv / parity-deconv, 1-D grid + XCD swizzle
// SUB = CLSN*COGN replicas per m-tile; swizzle puts all SUB replicas of a
// tile in one 64-index window, congruent mod 8 (same XCD under rr mapping).
template<int CI, int CO, int NTALL, int NT, int S, int IH, int IW, int OH, int OW,
         int NTAP, int KW, int STRIDE, int CLSN, int COGN, bool RELU, bool F32OUT>
__global__ __launch_bounds__(256, 4) void mconv_k(
    const unsigned short* __restrict__ in, const unsigned short* __restrict__ wb,
    const float* __restrict__ bias, void* __restrict__ outv,
    const unsigned short* __restrict__ zeropg) {
  const int KC = CI / 16;
  const int TSZ = KC * NT * 512;
  const int STG = KC * NT / 4;
  const int SUB = CLSN * COGN;
  const bool DECONV = (CLSN > 1);
  __shared__ unsigned short sB[2][TSZ];
  int tid = threadIdx.x, lane = tid & 63, wv = tid >> 6;
  // ---- XCD-aware swizzle ----
  int bi = blockIdx.x;
  int tile, sub;
  if (SUB == 8)      { tile = ((bi >> 6) << 3) | (bi & 7); sub = (bi >> 3) & 7; }
  else if (SUB == 2) { tile = ((bi >> 4) << 3) | (bi & 7); sub = (bi >> 3) & 1; }
  else               { tile = bi; sub = 0; }
  int cog = sub % COGN;
  int cls = sub / COGN;
  int m0 = tile * (128 * S) + wv * (32 * S);
  int ca = cls >> 1, cb2 = cls & 1;
  int khalf = lane >> 5;
  int n_[S], oh_[S], ow_[S];
  #pragma unroll
  for (int s = 0; s < S; ++s) {
    int mm = m0 + s * 32 + (lane & 31);
    n_[s] = mm / (OH * OW);
    int rem = mm % (OH * OW);
    oh_[s] = rem / OW; ow_[s] = rem % OW;
  }
  f32x16 acc[S][NT];
  #pragma unroll
  for (int s = 0; s < S; ++s)
    #pragma unroll
    for (int t = 0; t < NT; ++t)
      #pragma unroll
      for (int e = 0; e < 16; ++e) acc[s][t][e] = 0.f;

  const unsigned short* wcls = wb + (size_t)cls * NTAP * KC * NTALL * 512;
  uint4 st[STG];
  #pragma unroll
  for (int q = 0; q < STG; ++q) {
    int i = q * 256 + tid;
    int kc = i / (NT * 64), r = i - kc * (NT * 64);
    st[q] = *(const uint4*)(wcls + (size_t)(kc * NTALL + cog * NT) * 512 + r * 8);
  }
  #pragma unroll
  for (int q = 0; q < STG; ++q) {
    int i = q * 256 + tid;
    *(uint4*)&sB[0][i * 8] = st[q];
  }
  __syncthreads();

  for (int t = 0; t < NTAP; ++t) {
    int cur = t & 1;
    if (t + 1 < NTAP) {
      const unsigned short* wt = wcls + (size_t)(t + 1) * KC * NTALL * 512;
      #pragma unroll
      for (int q = 0; q < STG; ++q) {
        int i = q * 256 + tid;
        int kc = i / (NT * 64), r = i - kc * (NT * 64);
        st[q] = *(const uint4*)(wt + (size_t)(kc * NTALL + cog * NT) * 512 + r * 8);
      }
    }
    const unsigned short* ap[S];
    #pragma unroll
    for (int s = 0; s < S; ++s) {
      int ih, iw;
      if (DECONV) { ih = oh_[s] + ca - (t >> 1); iw = ow_[s] + cb2 - (t & 1); }
      else        { ih = STRIDE * oh_[s] - 1 + t / KW; iw = STRIDE * ow_[s] - 1 + t % KW; }
      bool valid = ((unsigned)ih < (unsigned)IH) && ((unsigned)iw < (unsigned)IW);
      ap[s] = valid ? (in + ((size_t)(n_[s] * IH + ih) * IW + iw) * CI + khalf * 8)
                    : (zeropg + khalf * 8);
    }
    #pragma unroll
    for (int kc = 0; kc < KC; ++kc) {
      short8 a[S];
      #pragma unroll
      for (int s = 0; s < S; ++s) a[s] = *(const short8*)(ap[s] + kc * 16);
      #pragma unroll
      for (int nt = 0; nt < NT; ++nt) {
        short8 b = *(const short8*)&sB[cur][(kc * NT + nt) * 512 + lane * 8];
        #pragma unroll
        for (int s = 0; s < S; ++s)
          acc[s][nt] = __builtin_amdgcn_mfma_f32_32x32x16_bf16(a[s], b, acc[s][nt], 0, 0, 0);
      }
    }
    if (t + 1 < NTAP) {
      #pragma unroll
      for (int q = 0; q < STG; ++q) {
        int i = q * 256 + tid;
        *(uint4*)&sB[cur ^ 1][i * 8] = st[q];
      }
    }
    __syncthreads();
  }

  int col = lane & 31;
  #pragma unroll
  for (int s = 0; s < S; ++s)
    #pragma unroll
    for (int nt = 0; nt < NT; ++nt) {
      int co = (cog * NT + nt) * 32 + col;
      float bv = bias[co];
      #pragma unroll
      for (int r = 0; r < 16; ++r) {
        int mrow = (r & 3) + 8 * (r >> 2) + 4 * khalf;
        int mp = m0 + s * 32 + mrow;
        int n2 = mp / (OH * OW), r2 = mp % (OH * OW);
        int oh2 = r2 / OW, ow2 = r2 % OW;
        float v = acc[s][nt][r] + bv;
        if (RELU) v = fmaxf(v, 0.f);
        size_t idx;
        if (DECONV)
          idx = ((size_t)(n2 * (2 * OH) + 2 * oh2 + ca) * (2 * OW) + 2 * ow2 + cb2) * CO + co;
        else
          idx = ((size_t)(n2 * OH + oh2) * OW + ow2) * CO + co;
        if (F32OUT) ((float*)outv)[idx] = v;
        else        ((unsigned short*)outv)[idx] = f2bf(v);
      }
    }
}

// ---------------- VQ via MFMA, codebook frags staged in LDS (2 phases x 32KB)
__global__ __launch_bounds__(256, 2) void vq2_k(
    const float* __restrict__ ze, const float* __restrict__ cb,
    const unsigned short* __restrict__ cbf, const float* __restrict__ cnorm,
    unsigned short* __restrict__ zq, float* __restrict__ acc_loss) {
  __shared__ unsigned short sC[16384];   // 8 tiles of B-frags (32 KB)
  __shared__ int s_idx[4][32];
  int tid = threadIdx.x, lane = tid & 63, wv = tid >> 6;
  int m0 = blockIdx.x * 128 + wv * 32;
  int col = lane & 31, khalf = lane >> 5;
  const float* zrow = ze + (size_t)(m0 + col) * 64 + khalf * 8;
  short8 af[4];
  #pragma unroll
  for (int kc = 0; kc < 4; ++kc) {
    float4 a = *(const float4*)(zrow + kc * 16);
    float4 b = *(const float4*)(zrow + kc * 16 + 4);
    short8 f;
    f[0] = (short)f2bf(a.x); f[1] = (short)f2bf(a.y);
    f[2] = (short)f2bf(a.z); f[3] = (short)f2bf(a.w);
    f[4] = (short)f2bf(b.x); f[5] = (short)f2bf(b.y);
    f[6] = (short)f2bf(b.z); f[7] = (short)f2bf(b.w);
    af[kc] = f;
  }
  float best[16]; int bidx[16];
  #pragma unroll
  for (int r = 0; r < 16; ++r) { best[r] = 3.4e38f; bidx[r] = 0; }
  for (int half = 0; half < 2; ++half) {
    #pragma unroll
    for (int q = 0; q < 8; ++q) {
      int i = q * 256 + tid;
      *(uint4*)&sC[i * 8] = *(const uint4*)(cbf + half * 16384 + i * 8);
    }
    __syncthreads();
    #pragma unroll
    for (int t8 = 0; t8 < 8; ++t8) {
      int tt = half * 8 + t8;
      f32x16 acc;
      #pragma unroll
      for (int e = 0; e < 16; ++e) acc[e] = 0.f;
      #pragma unroll
      for (int kc = 0; kc < 4; ++kc) {
        short8 bf_ = *(const short8*)&sC[(t8 * 4 + kc) * 512 + lane * 8];
        acc = __builtin_amdgcn_mfma_f32_32x32x16_bf16(af[kc], bf_, acc, 0, 0, 0);
      }
      float cn = cnorm[tt * 32 + col];
      int code = tt * 32 + col;
      #pragma unroll
      for (int r = 0; r < 16; ++r) {
        float d = fmaf(-2.f, acc[r], cn);
        if (d < best[r]) { best[r] = d; bidx[r] = code; }
      }
    }
    __syncthreads();
  }
  #pragma unroll
  for (int off = 1; off < 32; off <<= 1) {
    #pragma unroll
    for (int r = 0; r < 16; ++r) {
      float ob = __shfl_xor(best[r], off, 64);
      int   oi = __shfl_xor(bidx[r], off, 64);
      if (ob < best[r]) { best[r] = ob; bidx[r] = oi; }
    }
  }
  if (col == 0) {
    #pragma unroll
    for (int r = 0; r < 16; ++r)
      s_idx[wv][(r & 3) + 8 * (r >> 2) + 4 * khalf] = bidx[r];
  }
  __syncthreads();
  int row = lane >> 1, half2 = lane & 1;
  int m = m0 + row;
  int idx = s_idx[wv][row];
  const float4* crow = (const float4*)(cb + idx * 64 + half2 * 32);
  const float4* zp = (const float4*)(ze + (size_t)m * 64 + half2 * 32);
  uint2* zqp = (uint2*)(zq + (size_t)m * 64 + half2 * 32);
  float lsum = 0.f;
  #pragma unroll
  for (int q = 0; q < 8; ++q) {
    float4 c4 = crow[q];
    float4 z4 = zp[q];
    uint2 u; u.x = pack2bf(c4.x, c4.y); u.y = pack2bf(c4.z, c4.w);
    zqp[q] = u;
    float d;
    d = z4.x - c4.x; lsum = fmaf(d, d, lsum);
    d = z4.y - c4.y; lsum = fmaf(d, d, lsum);
    d = z4.z - c4.z; lsum = fmaf(d, d, lsum);
    d = z4.w - c4.w; lsum = fmaf(d, d, lsum);
  }
  #pragma unroll
  for (int off = 32; off > 0; off >>= 1) lsum += __shfl_down(lsum, off, 64);
  if (lane == 0) atomicAdd(acc_loss, lsum);
}

// ---------------- conv4: d2 NHWC bf16 -> x_recon NCHW fp32 (+recon loss)
// 16x16x32 MFMA, N=16; B in LDS; XCD swizzle groups 8 adjacent row-tiles.
__global__ __launch_bounds__(256, 4) void conv4_k(
    const unsigned short* __restrict__ in, const unsigned short* __restrict__ wb,
    const float* __restrict__ bias, const float* __restrict__ x,
    float* __restrict__ out, float* __restrict__ acc_loss,
    const unsigned short* __restrict__ zeropg) {
  __shared__ unsigned short sW[18432];   // 9 taps x 4 kc x 512 (36 KB)
  int tid = threadIdx.x, lane = tid & 63, wv = tid >> 6;
  #pragma unroll
  for (int q = 0; q < 9; ++q) {
    int i = q * 256 + tid;
    *(uint4*)&sW[i * 8] = *(const uint4*)(wb + i * 8);
  }
  // XCD swizzle: 8 consecutive tiles (sharing halo rows) -> same mod-8 class
  int bi = blockIdx.x;
  int t0 = (bi & ~63) | ((bi & 7) << 3) | ((bi >> 3) & 7);
  int m0 = t0 * 256 + wv * 64;
  int quad = lane >> 4, mloc = lane & 15;
  int n_[4], oh_[4], ow_[4];
  #pragma unroll
  for (int s = 0; s < 4; ++s) {
    int mm = m0 + s * 16 + mloc;
    n_[s] = mm >> 14;
    int rem = mm & 16383;
    oh_[s] = rem >> 7; ow_[s] = rem & 127;
  }
  f32x4 acc[4];
  #pragma unroll
  for (int s = 0; s < 4; ++s)
    #pragma unroll
    for (int e = 0; e < 4; ++e) acc[s][e] = 0.f;
  __syncthreads();
  #pragma unroll
  for (int t = 0; t < 9; ++t) {
    int dh = t / 3 - 1, dw = t % 3 - 1;
    const unsigned short* ap[4];
    #pragma unroll
    for (int s = 0; s < 4; ++s) {
      int ih = oh_[s] + dh, iw = ow_[s] + dw;
      bool valid = ((unsigned)ih < 128u) && ((unsigned)iw < 128u);
      ap[s] = valid ? (in + ((size_t)(n_[s] * 128 + ih) * 128 + iw) * 128 + quad * 8)
                    : (zeropg + quad * 8);
    }
    #pragma unroll
    for (int kc = 0; kc < 4; ++kc) {
      short8 bf_ = *(const short8*)&sW[(t * 4 + kc) * 512 + lane * 8];
      #pragma unroll
      for (int s = 0; s < 4; ++s) {
        short8 a = *(const short8*)(ap[s] + kc * 32);
        acc[s] = __builtin_amdgcn_mfma_f32_16x16x32_bf16(a, bf_, acc[s], 0, 0, 0);
      }
    }
  }
  int co = lane & 15;
  float bv = (co < 3) ? bias[co] : 0.f;
  float lsum = 0.f;
  #pragma unroll
  for (int s = 0; s < 4; ++s)
    #pragma unroll
    for (int r = 0; r < 4; ++r) {
      int m = m0 + s * 16 + quad * 4 + r;
      if (co < 3) {
        float v = acc[s][r] + bv;
        int n2 = m >> 14, r2 = m & 16383;
        int gi = (n2 * 3 + co) * 16384 + r2;
        out[gi] = v;
        float d = v - x[gi];
        lsum = fmaf(d, d, lsum);
      }
    }
  #pragma unroll
  for (int off = 32; off > 0; off >>= 1) lsum += __shfl_down(lsum, off, 64);
  if (lane == 0) atomicAdd(acc_loss, lsum);
}

// ---------------- finalize losses
__global__ void finalize_k(const float* __restrict__ accv, float* __restrict__ out) {
  if (threadIdx.x == 0 && blockIdx.x == 0) {
    float recon = accv[0] / 3145728.0f;
    float vq = 1.25f * accv[1] / 4194304.0f;
    out[3145728] = recon + vq;
    out[3145729] = recon;
    out[3145730] = vq;
  }
}

extern "C" void kernel_launch(void* const* d_in, const int* in_sizes, int n_in,
                              void* d_out, int out_size, void* d_ws, size_t ws_size,
                              hipStream_t stream) {
  const float* x   = (const float*)d_in[0];
  const float* ew1 = (const float*)d_in[1];
  const float* eb1 = (const float*)d_in[2];
  const float* ew2 = (const float*)d_in[3];
  const float* eb2 = (const float*)d_in[4];
  const float* ew3 = (const float*)d_in[5];
  const float* eb3 = (const float*)d_in[6];
  const float* cb  = (const float*)d_in[7];
  const float* dw1 = (const float*)d_in[8];
  const float* db1 = (const float*)d_in[9];
  const float* dw2 = (const float*)d_in[10];
  const float* db2 = (const float*)d_in[11];
  const float* dw3 = (const float*)d_in[12];
  const float* db3 = (const float*)d_in[13];
  float* out = (float*)d_out;

  char* ws = (char*)d_ws;
  float* acc = (float*)ws;                               // [0]=recon ss, [1]=vq ss
  unsigned short* zeropg = (unsigned short*)(ws + 256);  // 512B zero page
  char* p = ws + 1024;
  unsigned short* wb2  = (unsigned short*)p; p += 524288;  // conv2 16*8*4*512*2
  unsigned short* wb3  = (unsigned short*)p; p += 147456;  // conv3  9*8*2*512*2
  unsigned short* wb4  = (unsigned short*)p; p += 36864;   // conv4 9*4*512*2
  unsigned short* wbd1 = (unsigned short*)p; p += 262144;  // dc1 4*4*4*4*512*2
  unsigned short* wbd2 = (unsigned short*)p; p += 524288;  // dc2 4*4*8*4*512*2
  unsigned short* cbf  = (unsigned short*)p; p += 65536;   // cb frags
  float*          cnrm = (float*)p;          p += 2048;
  float*          wc1  = (float*)p;          p += 24576;   // conv1 [tap][co] fp32
  size_t fixed = (size_t)(p - ws);

  // full-batch intermediates
  unsigned short* h1 = (unsigned short*)p; p += 67108864ull;  // h1 / d1 slot
  unsigned short* h2 = (unsigned short*)p; p += 16777216ull;
  float*          ze = (float*)p;          p += 16777216ull;
  unsigned short* zq = (unsigned short*)p; p += 8388608ull;
  unsigned short* d2 = (unsigned short*)p;
  size_t base = fixed + 67108864ull + 16777216ull + 16777216ull + 8388608ull;
  int CD = 64;
  while (CD > 1 && base + (size_t)CD * 4194304ull > ws_size) CD >>= 1;

  hipMemsetAsync(ws, 0, 1024, stream);   // loss accumulators + zero page
  repack_conv_w<128, 16, 4><<<(16 * 8 * 4 * 512 + 255) / 256, 256, 0, stream>>>(ew2, wb2, 128);
  repack_conv_w<128, 9, 2><<<(9 * 8 * 2 * 512 + 255) / 256, 256, 0, stream>>>(ew3, wb3, 64);
  repack_conv4_w<<<(9 * 4 * 512 + 255) / 256, 256, 0, stream>>>(dw3, wb4);
  repack_deconv_w<64, 128, 4><<<(16 * 4 * 4 * 512 + 255) / 256, 256, 0, stream>>>(dw1, wbd1);
  repack_deconv_w<128, 128, 4><<<(16 * 8 * 4 * 512 + 255) / 256, 256, 0, stream>>>(dw2, wbd2);
  repack_cb<<<128, 256, 0, stream>>>(cb, cbf);
  cnorm_k<<<2, 256, 0, stream>>>(cb, cnrm);
  repack_conv1_w<<<24, 256, 0, stream>>>(ew1, wc1);

  // ---- encoder, full batch ----
  conv1_k<<<1024, 256, 0, stream>>>(x, wc1, eb1, h1);
  // conv2: 256 tiles x 2 cog = 512 blocks (swizzled 1-D)
  mconv_k<128, 128, 4, 2, 2, 64, 64, 32, 32, 16, 4, 2, 1, 2, true, false>
      <<<512, 256, 0, stream>>>(h1, wb2, eb2, h2, zeropg);
  // conv3: 256 tiles, no replication
  mconv_k<128, 64, 2, 2, 2, 32, 32, 32, 32, 9, 3, 1, 1, 1, false, true>
      <<<256, 256, 0, stream>>>(h2, wb3, eb3, ze, zeropg);
  vq2_k<<<512, 256, 0, stream>>>(ze, cb, cbf, cnrm, zq, acc + 1);
  // dc1: 256 tiles x (4 cls x 2 cog) = 2048 blocks (swizzled 1-D)
  mconv_k<64, 128, 4, 2, 2, 32, 32, 32, 32, 4, 2, 1, 4, 2, true, false>
      <<<2048, 256, 0, stream>>>(zq, wbd1, db1, h1, zeropg);

  // ---- decoder, full batch ----
  for (int n0 = 0; n0 < 64; n0 += CD) {
    const unsigned short* d1c = h1 + (size_t)n0 * 524288;   // 64*64*128
    // dc2: CD*16 tiles x 8 subs = CD*128 blocks (swizzled 1-D)
    mconv_k<128, 128, 4, 2, 2, 64, 64, 64, 64, 4, 2, 1, 4, 2, true, false>
        <<<CD * 128, 256, 0, stream>>>(d1c, wbd2, db2, d2, zeropg);
    // conv4: CD*64 blocks (swizzled 1-D)
    conv4_k<<<CD * 64, 256, 0, stream>>>(d2, wb4, db3, x + (size_t)n0 * 49152,
                                         out + (size_t)n0 * 49152, acc, zeropg);
  }
  finalize_k<<<1, 64, 0, stream>>>(acc, out);
}